// Round 10
// baseline (552.094 us; speedup 1.0000x reference)
//
#include <hip/hip_runtime.h>

// Shapes: b=2, L=2048, d_model=1024, d_inner=2048, d_state=16, dt_rank=64, d_conv=4
// Pipelined 256x256 bf16x3 MFMA for in-proj; 128x64-tile MFMA for out-proj;
// split-K=16 MFMA for x_dbl; fused reduce+delta matvec; chunked 3-pass scan.

typedef unsigned short ushort_t;
using short8 = __attribute__((ext_vector_type(8))) short;
using f32x4  = __attribute__((ext_vector_type(4))) float;
using gptr_t = const __attribute__((address_space(1))) unsigned short*;
using sptr_t = __attribute__((address_space(3))) unsigned short*;

#define NC 64   // chunks
#define CL 32   // chunk length  (NC*CL == 2048)

__device__ inline ushort_t f2bf(float v) {
    unsigned u = __float_as_uint(v);
    unsigned r = (u + 0x7fff + ((u >> 16) & 1)) >> 16;   // RNE
    return (ushort_t)r;
}
__device__ inline float bf2f(ushort_t h) { return __uint_as_float(((unsigned)h) << 16); }
__device__ inline void split2(float v, ushort_t& h, ushort_t& l) {
    h = f2bf(v);
    l = f2bf(v - bf2f(h));
}

// ---------------- merged converters (one launch) ----------------
__global__ __launch_bounds__(256) void convert_all(
    const float* __restrict__ x, ushort_t* __restrict__ xh, ushort_t* __restrict__ xl,
    const float* __restrict__ W_in, ushort_t* __restrict__ winh, ushort_t* __restrict__ winl,
    const float* __restrict__ W_out, ushort_t* __restrict__ wouth, ushort_t* __restrict__ woutl,
    const float* __restrict__ W_x, ushort_t* __restrict__ wxh, ushort_t* __restrict__ wxl) {
    __shared__ float tile[32][33];
    const int id = blockIdx.x;
    if (id < 4096) {
        int i = id * 256 + threadIdx.x;
        float4 v = ((const float4*)x)[i];
        ushort4 hh, ll;
        split2(v.x, hh.x, ll.x); split2(v.y, hh.y, ll.y);
        split2(v.z, hh.z, ll.z); split2(v.w, hh.w, ll.w);
        ((ushort4*)xh)[i] = hh;
        ((ushort4*)xl)[i] = ll;
        return;
    }
    const float* W; ushort_t *Th, *Tl; int K, N, bx, by;
    if (id < 8192)       { W = W_in;  Th = winh;  Tl = winl;  K = 1024; N = 4096;
                           bx = (id - 4096) & 127; by = (id - 4096) >> 7; }
    else if (id < 10240) { W = W_out; Th = wouth; Tl = woutl; K = 2048; N = 1024;
                           bx = (id - 8192) & 31;  by = (id - 8192) >> 5; }
    else                 { W = W_x;   Th = wxh;   Tl = wxl;   K = 2048; N = 96;
                           bx = (id - 10240) & 3;  by = (id - 10240) >> 2; }
    int n0 = bx * 32, k0 = by * 32;
    int tx = threadIdx.x & 31, ty = threadIdx.x >> 5;
    #pragma unroll
    for (int j = 0; j < 4; ++j) {
        int k = ty + j * 8;
        tile[k][tx] = (n0 + tx < N) ? W[(size_t)(k0 + k) * N + n0 + tx] : 0.f;
    }
    __syncthreads();
    #pragma unroll
    for (int j = 0; j < 4; ++j) {
        int nrow = ty + j * 8;
        float v = tile[tx][nrow];
        ushort_t h, l;
        split2(v, h, l);
        size_t o = (size_t)(n0 + nrow) * K + k0 + tx;
        Th[o] = h; Tl[o] = l;
    }
}

// ======== 256x256 8-wave pipelined bf16x3 GEMM (counted vmcnt, T2 swizzle) ====
__global__ __launch_bounds__(512, 2) void gemm_mfma3_256(
    const ushort_t* __restrict__ Ah, const ushort_t* __restrict__ Al,
    const ushort_t* __restrict__ Bh, const ushort_t* __restrict__ Bl,
    float* __restrict__ C, int M, int N, int K, int ksteps) {
    __shared__ ushort_t lds[65536];   // 128 KB
    const int tid  = threadIdx.x;
    const int w    = tid >> 6;
    const int lane = tid & 63;
    const int wr = w >> 2;
    const int wc = w & 3;
    const int fr = lane & 15;
    const int kq = (lane >> 4) * 8;
    const int bm = blockIdx.y * 256;
    const int bn = blockIdx.x * 256;
    const int NT = ksteps;

    const int sg   = tid ^ ((tid >> 3) & 7);
    const int srow = sg >> 2;
    const int skof = (sg & 3) * 8;

    f32x4 acc[8][4];
    #pragma unroll
    for (int i = 0; i < 8; ++i)
        #pragma unroll
        for (int j = 0; j < 4; ++j) acc[i][j] = (f32x4){0.f, 0.f, 0.f, 0.f};

    #define STAGE(t, db)                                                          \
    {                                                                             \
        const int k0_ = (t) * 32;                                                 \
        _Pragma("unroll")                                                         \
        for (int h_ = 0; h_ < 2; ++h_) {                                          \
            const size_t ga_ = (size_t)(bm + h_ * 128 + srow) * K + k0_ + skof;   \
            const size_t gb_ = (size_t)(bn + h_ * 128 + srow) * K + k0_ + skof;   \
            const int dst_ = (db) * 8192 + h_ * 4096 + w * 512;                   \
            __builtin_amdgcn_global_load_lds((gptr_t)(Ah + ga_), (sptr_t)&lds[0     + dst_], 16, 0, 0); \
            __builtin_amdgcn_global_load_lds((gptr_t)(Al + ga_), (sptr_t)&lds[16384 + dst_], 16, 0, 0); \
            __builtin_amdgcn_global_load_lds((gptr_t)(Bh + gb_), (sptr_t)&lds[32768 + dst_], 16, 0, 0); \
            __builtin_amdgcn_global_load_lds((gptr_t)(Bl + gb_), (sptr_t)&lds[49152 + dst_], 16, 0, 0); \
        }                                                                         \
    }

    #define LDF(arrOff, db, row) \
        (*(const short8*)&lds[(arrOff) + (db) * 8192 + \
            ((((row) << 2) | (kq >> 3)) ^ (((row) >> 1) & 7)) * 8])

    STAGE(0, 0);
    STAGE(1, 1);
    asm volatile("s_waitcnt vmcnt(8)" ::: "memory");
    __builtin_amdgcn_s_barrier();

    for (int t = 0; t < NT; ++t) {
        const int db = t & 1;
        short8 bhF[4], blF[4], ahF[4], alF[4];
        #pragma unroll
        for (int j = 0; j < 4; ++j) {
            const int rowb = wc * 64 + j * 16 + fr;
            bhF[j] = LDF(32768, db, rowb);
            blF[j] = LDF(49152, db, rowb);
        }
        #pragma unroll
        for (int i = 0; i < 4; ++i) {
            const int rowa = wr * 128 + i * 16 + fr;
            ahF[i] = LDF(0, db, rowa);
            alF[i] = LDF(16384, db, rowa);
        }
        __builtin_amdgcn_s_setprio(1);
        #pragma unroll
        for (int i = 0; i < 4; ++i)
            #pragma unroll
            for (int j = 0; j < 4; ++j) {
                acc[i][j] = __builtin_amdgcn_mfma_f32_16x16x32_bf16(ahF[i], bhF[j], acc[i][j], 0, 0, 0);
                acc[i][j] = __builtin_amdgcn_mfma_f32_16x16x32_bf16(ahF[i], blF[j], acc[i][j], 0, 0, 0);
                acc[i][j] = __builtin_amdgcn_mfma_f32_16x16x32_bf16(alF[i], bhF[j], acc[i][j], 0, 0, 0);
            }
        __builtin_amdgcn_s_setprio(0);
        short8 ah2[4], al2[4];
        #pragma unroll
        for (int i = 0; i < 4; ++i) {
            const int rowa = wr * 128 + (i + 4) * 16 + fr;
            ah2[i] = LDF(0, db, rowa);
            al2[i] = LDF(16384, db, rowa);
        }
        asm volatile("s_waitcnt lgkmcnt(0)" ::: "memory");
        __builtin_amdgcn_sched_barrier(0);
        __builtin_amdgcn_s_barrier();
        if (t + 2 < NT) STAGE(t + 2, db);
        __builtin_amdgcn_s_setprio(1);
        #pragma unroll
        for (int i = 0; i < 4; ++i)
            #pragma unroll
            for (int j = 0; j < 4; ++j) {
                acc[i + 4][j] = __builtin_amdgcn_mfma_f32_16x16x32_bf16(ah2[i], bhF[j], acc[i + 4][j], 0, 0, 0);
                acc[i + 4][j] = __builtin_amdgcn_mfma_f32_16x16x32_bf16(ah2[i], blF[j], acc[i + 4][j], 0, 0, 0);
                acc[i + 4][j] = __builtin_amdgcn_mfma_f32_16x16x32_bf16(al2[i], bhF[j], acc[i + 4][j], 0, 0, 0);
            }
        __builtin_amdgcn_s_setprio(0);
        if (t + 2 < NT) {
            asm volatile("s_waitcnt vmcnt(8)" ::: "memory");
        } else {
            asm volatile("s_waitcnt vmcnt(0)" ::: "memory");
        }
        __builtin_amdgcn_sched_barrier(0);
        __builtin_amdgcn_s_barrier();
    }
    #undef STAGE
    #undef LDF

    #pragma unroll
    for (int i = 0; i < 8; ++i) {
        const int row = bm + wr * 128 + i * 16 + (lane >> 4) * 4;
        #pragma unroll
        for (int j = 0; j < 4; ++j) {
            const int col = bn + wc * 64 + j * 16 + fr;
            float* cp = C + (size_t)row * N + col;
            #pragma unroll
            for (int r = 0; r < 4; ++r) cp[(size_t)r * N] = acc[i][j][r];
        }
    }
}

// ---- 128x64-tile variant (4 waves as 2Mx2N, per-wave 64x32) for out-proj ----
__global__ __launch_bounds__(256) void gemm_mfma3_n64(
    const ushort_t* __restrict__ Ah, const ushort_t* __restrict__ Al,
    const ushort_t* __restrict__ Bh, const ushort_t* __restrict__ Bl,
    float* __restrict__ C, int M, int N, int K) {
    __shared__ ushort_t sAh[4096], sAl[4096], sBh[2048], sBl[2048];
    const int tid  = threadIdx.x;
    const int wid  = tid >> 6;
    const int lane = tid & 63;
    const int bm = blockIdx.y * 128;
    const int bn = blockIdx.x * 64;
    const int wr = wid >> 1, wc = wid & 1;

    f32x4 acc[4][2];
    #pragma unroll
    for (int i = 0; i < 4; ++i)
        #pragma unroll
        for (int j = 0; j < 2; ++j) acc[i][j] = (f32x4){0.f, 0.f, 0.f, 0.f};

    for (int k0 = 0; k0 < K; k0 += 32) {
        #pragma unroll
        for (int issue = 0; issue < 2; ++issue) {
            const int off = issue * 4096 + tid * 16;
            const int row = off >> 6;
            const int ce  = (off & 63) >> 1;
            const size_t ga = (size_t)(bm + row) * K + k0 + ce;
            const int lo = (issue * 4096 + wid * 1024) >> 1;
            __builtin_amdgcn_global_load_lds((gptr_t)(Ah + ga), (sptr_t)&sAh[lo], 16, 0, 0);
            __builtin_amdgcn_global_load_lds((gptr_t)(Al + ga), (sptr_t)&sAl[lo], 16, 0, 0);
        }
        {
            const int off = tid * 16;
            const int row = off >> 6;
            const int ce  = (off & 63) >> 1;
            const size_t gb = (size_t)(bn + row) * K + k0 + ce;
            const int lo = (wid * 1024) >> 1;
            __builtin_amdgcn_global_load_lds((gptr_t)(Bh + gb), (sptr_t)&sBh[lo], 16, 0, 0);
            __builtin_amdgcn_global_load_lds((gptr_t)(Bl + gb), (sptr_t)&sBl[lo], 16, 0, 0);
        }
        __syncthreads();

        const int fr = lane & 15;
        const int kb = (lane >> 4) * 8;
        short8 ah[4], al[4], bh[2], bl[2];
        #pragma unroll
        for (int i = 0; i < 4; ++i) {
            const int ra = (wr * 64 + i * 16 + fr) * 32 + kb;
            ah[i] = *(const short8*)&sAh[ra];
            al[i] = *(const short8*)&sAl[ra];
        }
        #pragma unroll
        for (int j = 0; j < 2; ++j) {
            const int rb = (wc * 32 + j * 16 + fr) * 32 + kb;
            bh[j] = *(const short8*)&sBh[rb];
            bl[j] = *(const short8*)&sBl[rb];
        }
        #pragma unroll
        for (int i = 0; i < 4; ++i)
            #pragma unroll
            for (int j = 0; j < 2; ++j) {
                acc[i][j] = __builtin_amdgcn_mfma_f32_16x16x32_bf16(ah[i], bh[j], acc[i][j], 0, 0, 0);
                acc[i][j] = __builtin_amdgcn_mfma_f32_16x16x32_bf16(ah[i], bl[j], acc[i][j], 0, 0, 0);
                acc[i][j] = __builtin_amdgcn_mfma_f32_16x16x32_bf16(al[i], bh[j], acc[i][j], 0, 0, 0);
            }
        __syncthreads();
    }

    #pragma unroll
    for (int i = 0; i < 4; ++i) {
        int row = bm + wr * 64 + i * 16 + (lane >> 4) * 4;
        #pragma unroll
        for (int j = 0; j < 2; ++j) {
            int col = bn + wc * 32 + j * 16 + (lane & 15);
            float* cp = C + (size_t)row * N + col;
            #pragma unroll
            for (int r = 0; r < 4; ++r) cp[(size_t)r * N] = acc[i][j][r];
        }
    }
}

// Split-K=16 for xdbl = xs @ W_x (M=4096, Npad=128 but only 96 stored).
__global__ __launch_bounds__(256) void gemm_mfma3_sk(
    const ushort_t* __restrict__ Ah, const ushort_t* __restrict__ Al,
    const ushort_t* __restrict__ Bh, const ushort_t* __restrict__ Bl,
    float* __restrict__ partial, int K) {
    __shared__ ushort_t sAh[4096], sAl[4096], sBh[4096], sBl[4096];
    const int tid  = threadIdx.x;
    const int wid  = tid >> 6;
    const int lane = tid & 63;
    const int kslice = blockIdx.x;
    const int bm = blockIdx.y * 128;
    const int wr = wid >> 1, wc = wid & 1;
    const int kbeg = kslice * 128;

    f32x4 acc[4][4];
    #pragma unroll
    for (int i = 0; i < 4; ++i)
        #pragma unroll
        for (int j = 0; j < 4; ++j) acc[i][j] = (f32x4){0.f, 0.f, 0.f, 0.f};

    for (int k0 = kbeg; k0 < kbeg + 128; k0 += 32) {
        #pragma unroll
        for (int issue = 0; issue < 2; ++issue) {
            const int off = wid * 2048 + issue * 1024 + lane * 16;
            const int row = off >> 6;
            const int ce  = (off & 63) >> 1;
            const size_t ga = (size_t)(bm + row) * K + k0 + ce;
            const size_t gb = (size_t)row * K + k0 + ce;
            const int lo = (wid * 2048 + issue * 1024) >> 1;
            __builtin_amdgcn_global_load_lds((gptr_t)(Ah + ga), (sptr_t)&sAh[lo], 16, 0, 0);
            __builtin_amdgcn_global_load_lds((gptr_t)(Al + ga), (sptr_t)&sAl[lo], 16, 0, 0);
            __builtin_amdgcn_global_load_lds((gptr_t)(Bh + gb), (sptr_t)&sBh[lo], 16, 0, 0);
            __builtin_amdgcn_global_load_lds((gptr_t)(Bl + gb), (sptr_t)&sBl[lo], 16, 0, 0);
        }
        __syncthreads();

        const int fr = lane & 15;
        const int kb = (lane >> 4) * 8;
        short8 ah[4], al[4], bh[4], bl[4];
        #pragma unroll
        for (int i = 0; i < 4; ++i) {
            const int ra = (wr * 64 + i * 16 + fr) * 32 + kb;
            ah[i] = *(const short8*)&sAh[ra];
            al[i] = *(const short8*)&sAl[ra];
            const int rb = (wc * 64 + i * 16 + fr) * 32 + kb;
            bh[i] = *(const short8*)&sBh[rb];
            bl[i] = *(const short8*)&sBl[rb];
        }
        #pragma unroll
        for (int i = 0; i < 4; ++i)
            #pragma unroll
            for (int j = 0; j < 4; ++j) {
                acc[i][j] = __builtin_amdgcn_mfma_f32_16x16x32_bf16(ah[i], bh[j], acc[i][j], 0, 0, 0);
                acc[i][j] = __builtin_amdgcn_mfma_f32_16x16x32_bf16(ah[i], bl[j], acc[i][j], 0, 0, 0);
                acc[i][j] = __builtin_amdgcn_mfma_f32_16x16x32_bf16(al[i], bh[j], acc[i][j], 0, 0, 0);
            }
        __syncthreads();
    }

    float* Cp = partial + (size_t)kslice * 4096 * 96;
    #pragma unroll
    for (int i = 0; i < 4; ++i) {
        int row = bm + wr * 64 + i * 16 + (lane >> 4) * 4;
        #pragma unroll
        for (int j = 0; j < 4; ++j) {
            int col = wc * 64 + j * 16 + (lane & 15);
            if (col < 96) {
                float* cp = Cp + (size_t)row * 96 + col;
                #pragma unroll
                for (int r = 0; r < 4; ++r) cp[(size_t)r * 96] = acc[i][j][r];
            }
        }
    }
}

// Fused: reduce 16 K-slice partials -> xdbl cols 64..95 (B,C) + LDS dt_in;
// then delta = softplus(dt_in @ W_dt + b_dt) as fp32 VALU matvec.
__global__ __launch_bounds__(256) void reduce_delta(
    const float4* __restrict__ p,      // 16 x (4096 x 24 f4), packed N=96
    float* __restrict__ xdbl,          // stride 128; write f4 idx 16..23
    const float* __restrict__ W_dt,    // 64 x 2048 row-major
    const float* __restrict__ b_dt,    // 2048
    float* __restrict__ delta) {       // 4096 x 2048
    __shared__ float rows[16][96];
    const int r0 = blockIdx.x * 16;
    for (int j = threadIdx.x; j < 384; j += 256) {
        int row = j / 24, c4 = j % 24;
        size_t idx = (size_t)(r0 + row) * 24 + c4;
        float4 s = p[idx];
        #pragma unroll
        for (int k = 1; k < 16; ++k) {
            float4 v = p[idx + (size_t)k * 98304];
            s.x += v.x; s.y += v.y; s.z += v.z; s.w += v.w;
        }
        *(float4*)&rows[row][c4 * 4] = s;
        if (c4 >= 16)
            ((float4*)(xdbl + (size_t)(r0 + row) * 128))[c4] = s;   // cols 64..95
    }
    __syncthreads();
    const int c = threadIdx.x * 8;
    float acc[16][8];
    #pragma unroll
    for (int r = 0; r < 16; ++r)
        #pragma unroll
        for (int j = 0; j < 8; ++j) acc[r][j] = 0.f;
    for (int k = 0; k < 64; ++k) {
        float4 w0 = *(const float4*)&W_dt[(size_t)k * 2048 + c];
        float4 w1 = *(const float4*)&W_dt[(size_t)k * 2048 + c + 4];
        float wv[8] = {w0.x, w0.y, w0.z, w0.w, w1.x, w1.y, w1.z, w1.w};
        #pragma unroll
        for (int r = 0; r < 16; ++r) {
            float dv = rows[r][k];
            #pragma unroll
            for (int j = 0; j < 8; ++j) acc[r][j] = fmaf(dv, wv[j], acc[r][j]);
        }
    }
    float4 b0 = *(const float4*)&b_dt[c];
    float4 b1 = *(const float4*)&b_dt[c + 4];
    float bv[8] = {b0.x, b0.y, b0.z, b0.w, b1.x, b1.y, b1.z, b1.w};
    #pragma unroll
    for (int r = 0; r < 16; ++r) {
        float o[8];
        #pragma unroll
        for (int j = 0; j < 8; ++j) {
            float v = acc[r][j] + bv[j];
            o[j] = (v > 20.f) ? v : log1pf(__expf(v));
        }
        float* dp = delta + (size_t)(r0 + r) * 2048 + c;
        *(float4*)dp       = make_float4(o[0], o[1], o[2], o[3]);
        *(float4*)(dp + 4) = make_float4(o[4], o[5], o[6], o[7]);
    }
}

// ---------------- conv + silu -> xs as bf16 hi/lo ----------------
__global__ void conv_silu_k(const float* __restrict__ xr, const float* __restrict__ Wc,
                            const float* __restrict__ bc,
                            ushort_t* __restrict__ xsh, ushort_t* __restrict__ xsl,
                            int total) {
    for (int idx = blockIdx.x * blockDim.x + threadIdx.x; idx < total;
         idx += gridDim.x * blockDim.x) {
        int d = idx & 2047;
        int l = (idx >> 11) & 2047;
        int b = idx >> 22;
        float acc = bc[d];
        const float* wp = Wc + d * 4;
        #pragma unroll
        for (int k = 0; k < 4; ++k) {
            int ll = l - 3 + k;
            if (ll >= 0)
                acc = fmaf(xr[((size_t)(b * 2048 + ll) << 12) + d], wp[k], acc);
        }
        float v = acc / (1.f + __expf(-acc));
        ushort_t h, lo;
        split2(v, h, lo);
        xsh[idx] = h;
        xsl[idx] = lo;
    }
}

// ---------------- chunked selective scan, n in registers ----------------
__global__ __launch_bounds__(256) void scan_p1(
    const float* __restrict__ delta,
    const ushort_t* __restrict__ xsh, const ushort_t* __restrict__ xsl,
    const float* __restrict__ xdbl, const float* __restrict__ A_log,
    float* __restrict__ S, float* __restrict__ sumdt) {
    const int u = blockIdx.x * 256 + threadIdx.x;
    const int chunk = u >> 12;
    const int c = u & 4095;
    const int b = c >> 11, d = c & 2047;

    float a[16];
    #pragma unroll
    for (int i = 0; i < 4; ++i) {
        float4 v = ((const float4*)(A_log + d * 16))[i];
        a[4 * i + 0] = -__expf(v.x); a[4 * i + 1] = -__expf(v.y);
        a[4 * i + 2] = -__expf(v.z); a[4 * i + 3] = -__expf(v.w);
    }
    float h[16];
    #pragma unroll
    for (int n = 0; n < 16; ++n) h[n] = 0.f;
    float sdt = 0.f;

    const size_t row0 = (size_t)b * 2048 + (size_t)chunk * CL;
    const float4* xd4 = (const float4*)xdbl;
    #pragma unroll 2
    for (int t = 0; t < CL; ++t) {
        const size_t row = row0 + t;
        float dt = delta[row * 2048 + d];
        float xv = bf2f(xsh[row * 2048 + d]) + bf2f(xsl[row * 2048 + d]);
        float4 Bv[4];
        #pragma unroll
        for (int i = 0; i < 4; ++i) Bv[i] = xd4[row * 32 + 16 + i];
        const float* Bf = (const float*)Bv;
        sdt += dt;
        float du = dt * xv;
        #pragma unroll
        for (int n = 0; n < 16; ++n) {
            float dA = __expf(dt * a[n]);
            h[n] = fmaf(dA, h[n], du * Bf[n]);
        }
    }
    float4* S4 = (float4*)(S + ((size_t)chunk * 4096 + c) * 16);
    #pragma unroll
    for (int i = 0; i < 4; ++i)
        S4[i] = make_float4(h[4 * i + 0], h[4 * i + 1], h[4 * i + 2], h[4 * i + 3]);
    sumdt[chunk * 4096 + c] = sdt;
}

__global__ __launch_bounds__(256) void scan_p2(
    float* __restrict__ S, const float* __restrict__ sumdt,
    const float* __restrict__ A_log) {
    const int idx = blockIdx.x * blockDim.x + threadIdx.x;
    const int n = idx & 15;
    const int c = (idx >> 4) & 4095;
    const int d = c & 2047;
    const float a = -__expf(A_log[d * 16 + n]);
    float h = 0.f;
    for (int k = 0; k < NC; ++k) {
        const size_t o = ((size_t)k * 4096 + c) * 16 + n;
        float carry = S[o];
        S[o] = h;
        float P = __expf(a * sumdt[k * 4096 + c]);
        h = fmaf(P, h, carry);
    }
}

__global__ __launch_bounds__(256) void scan_p3(
    const float* __restrict__ delta,
    const ushort_t* __restrict__ xsh, const ushort_t* __restrict__ xsl,
    const float* __restrict__ xdbl, const float* __restrict__ xr,
    const float* __restrict__ A_log, const float* __restrict__ Dp,
    const float* __restrict__ H0,
    ushort_t* __restrict__ yh, ushort_t* __restrict__ yl) {
    const int u = blockIdx.x * 256 + threadIdx.x;
    const int chunk = u >> 12;
    const int c = u & 4095;
    const int b = c >> 11, d = c & 2047;

    float a[16];
    #pragma unroll
    for (int i = 0; i < 4; ++i) {
        float4 v = ((const float4*)(A_log + d * 16))[i];
        a[4 * i + 0] = -__expf(v.x); a[4 * i + 1] = -__expf(v.y);
        a[4 * i + 2] = -__expf(v.z); a[4 * i + 3] = -__expf(v.w);
    }
    float h[16];
    const float4* H4 = (const float4*)(H0 + ((size_t)chunk * 4096 + c) * 16);
    #pragma unroll
    for (int i = 0; i < 4; ++i) {
        float4 v = H4[i];
        h[4 * i + 0] = v.x; h[4 * i + 1] = v.y; h[4 * i + 2] = v.z; h[4 * i + 3] = v.w;
    }
    const float Dd = Dp[d];

    const size_t row0 = (size_t)b * 2048 + (size_t)chunk * CL;
    const float4* xd4 = (const float4*)xdbl;
    #pragma unroll 2
    for (int t = 0; t < CL; ++t) {
        const size_t row = row0 + t;
        float dt = delta[row * 2048 + d];
        float xv = bf2f(xsh[row * 2048 + d]) + bf2f(xsl[row * 2048 + d]);
        float4 BC[8];
        #pragma unroll
        for (int i = 0; i < 8; ++i) BC[i] = xd4[row * 32 + 16 + i];
        const float* Bf = (const float*)BC;
        const float* Cf = Bf + 16;
        float du = dt * xv;
        float acc = 0.f;
        #pragma unroll
        for (int n = 0; n < 16; ++n) {
            float dA = __expf(dt * a[n]);
            h[n] = fmaf(dA, h[n], du * Bf[n]);
            acc = fmaf(h[n], Cf[n], acc);
        }
        float rv = xr[(row << 12) + 2048 + d];
        float yv = fmaf(Dd, xv, acc) * (rv / (1.f + __expf(-rv)));
        ushort_t hb, lb;
        split2(yv, hb, lb);
        yh[row * 2048 + d] = hb;
        yl[row * 2048 + d] = lb;
    }
}

// ---------------- launch ----------------
extern "C" void kernel_launch(void* const* d_in, const int* in_sizes, int n_in,
                              void* d_out, int out_size, void* d_ws, size_t ws_size,
                              hipStream_t stream) {
    const float* x      = (const float*)d_in[0];
    const float* W_in   = (const float*)d_in[1];
    const float* W_conv = (const float*)d_in[2];
    const float* b_conv = (const float*)d_in[3];
    const float* W_x    = (const float*)d_in[4];
    const float* W_dt   = (const float*)d_in[5];
    const float* b_dt   = (const float*)d_in[6];
    const float* A_log  = (const float*)d_in[7];
    const float* Dp     = (const float*)d_in[8];
    const float* W_out  = (const float*)d_in[9];
    float* out = (float*)d_out;

    float* ws    = (float*)d_ws;
    float* xr    = ws;                      // 16,777,216 f
    float* xdbl  = xr + 16777216;           //    524,288 f (4096 x 128)
    float* delta = xdbl + 524288;           //  8,388,608 f
    float* S     = delta + 8388608;         //  4,194,304 f
    float* sumdt = S + 4194304;             //    262,144 f
    ushort_t* base = (ushort_t*)(sumdt + 262144);
    ushort_t* xh = base, *xl = base + 4194304;
    ushort_t* winh = base + 8388608, *winl = base + 12582912;
    float*    partial = (float*)base;                 // sk partials (25.2 MB)
    ushort_t* yh = base, *yl = base + 8388608;        // written in p3
    ushort_t* wouth = base + 16777216, *woutl = base + 18874368;
    ushort_t* wxh   = base + 20971520, *wxl   = base + 21233664;
    ushort_t* xsh   = base + 22282240, *xsl   = base + 30670848;

    dim3 blk(256);

    convert_all<<<dim3(10496), blk, 0, stream>>>(x, xh, xl, W_in, winh, winl,
                                                 W_out, wouth, woutl, W_x, wxh, wxl);

    // 1) xr = x @ W_in   (4096 x 4096 x 1024), pipelined 256x256
    gemm_mfma3_256<<<dim3(16, 16), dim3(512), 0, stream>>>(
        xh, xl, winh, winl, xr, 4096, 4096, 1024, 32);
    // 2) xs = silu(dwconv(xr[:, :2048]) + b_conv) -> bf16 hi/lo
    conv_silu_k<<<dim3(4096), blk, 0, stream>>>(xr, W_conv, b_conv, xsh, xsl, 8388608);
    // 3) xdbl = xs @ W_x  (split-K=16 MFMA)
    gemm_mfma3_sk<<<dim3(16, 32), blk, 0, stream>>>(xsh, xsl, wxh, wxl, partial, 2048);
    // 3b+4) fused reduce + delta matvec + softplus
    reduce_delta<<<dim3(256), blk, 0, stream>>>((const float4*)partial, xdbl,
                                                W_dt, b_dt, delta);
    // 5) chunked scan
    scan_p1<<<dim3(1024), blk, 0, stream>>>(delta, xsh, xsl, xdbl, A_log, S, sumdt);
    scan_p2<<<dim3(256), blk, 0, stream>>>(S, sumdt, A_log);
    scan_p3<<<dim3(1024), blk, 0, stream>>>(delta, xsh, xsl, xdbl, xr, A_log, Dp, S, yh, yl);
    // 6) out = y @ W_out  (4096 x 1024 x 2048), 128x64-tile (512 blocks)
    gemm_mfma3_n64<<<dim3(16, 32), blk, 0, stream>>>(yh, yl, wouth, woutl, out,
                                                     4096, 1024, 2048);
}

// Round 12
// 508.454 us; speedup vs baseline: 1.0858x; 1.0858x over previous
//
#include <hip/hip_runtime.h>

// Shapes: b=2, L=2048, d_model=1024, d_inner=2048, d_state=16, dt_rank=64, d_conv=4
// CONFIG-A (R8 anchor): pipelined 256x256 bf16x3 MFMA in-proj; 128x64-tile
// out-proj; split-K=16 MFMA x_dbl + reduce16split; MFMA delta GEMM (K=64);
// chunked 3-pass scan, n-in-registers.

typedef unsigned short ushort_t;
using short8 = __attribute__((ext_vector_type(8))) short;
using f32x4  = __attribute__((ext_vector_type(4))) float;
using gptr_t = const __attribute__((address_space(1))) unsigned short*;
using sptr_t = __attribute__((address_space(3))) unsigned short*;

#define NC 64   // chunks
#define CL 32   // chunk length  (NC*CL == 2048)

__device__ inline ushort_t f2bf(float v) {
    unsigned u = __float_as_uint(v);
    unsigned r = (u + 0x7fff + ((u >> 16) & 1)) >> 16;   // RNE
    return (ushort_t)r;
}
__device__ inline float bf2f(ushort_t h) { return __uint_as_float(((unsigned)h) << 16); }
__device__ inline void split2(float v, ushort_t& h, ushort_t& l) {
    h = f2bf(v);
    l = f2bf(v - bf2f(h));
}

// ---------------- merged converters (one launch) ----------------
// seg0: split x (4096); seg1: W_in^T (4096); seg2: W_out^T (2048);
// seg3: W_x^T pad->128 (256); seg4: W_dt^T (128). Total 10624 blocks.
__global__ __launch_bounds__(256) void convert_all(
    const float* __restrict__ x, ushort_t* __restrict__ xh, ushort_t* __restrict__ xl,
    const float* __restrict__ W_in, ushort_t* __restrict__ winh, ushort_t* __restrict__ winl,
    const float* __restrict__ W_out, ushort_t* __restrict__ wouth, ushort_t* __restrict__ woutl,
    const float* __restrict__ W_x, ushort_t* __restrict__ wxh, ushort_t* __restrict__ wxl,
    const float* __restrict__ W_dt, ushort_t* __restrict__ wdth, ushort_t* __restrict__ wdtl) {
    __shared__ float tile[32][33];
    const int id = blockIdx.x;
    if (id < 4096) {
        int i = id * 256 + threadIdx.x;
        float4 v = ((const float4*)x)[i];
        ushort4 hh, ll;
        split2(v.x, hh.x, ll.x); split2(v.y, hh.y, ll.y);
        split2(v.z, hh.z, ll.z); split2(v.w, hh.w, ll.w);
        ((ushort4*)xh)[i] = hh;
        ((ushort4*)xl)[i] = ll;
        return;
    }
    const float* W; ushort_t *Th, *Tl; int K, N, bx, by;
    if (id < 8192)       { W = W_in;  Th = winh;  Tl = winl;  K = 1024; N = 4096;
                           bx = (id - 4096) & 127; by = (id - 4096) >> 7; }
    else if (id < 10240) { W = W_out; Th = wouth; Tl = woutl; K = 2048; N = 1024;
                           bx = (id - 8192) & 31;  by = (id - 8192) >> 5; }
    else if (id < 10496) { W = W_x;   Th = wxh;   Tl = wxl;   K = 2048; N = 96;
                           bx = (id - 10240) & 3;  by = (id - 10240) >> 2; }
    else                 { W = W_dt;  Th = wdth;  Tl = wdtl;  K = 64;   N = 2048;
                           bx = (id - 10496) & 63; by = (id - 10496) >> 6; }
    int n0 = bx * 32, k0 = by * 32;
    int tx = threadIdx.x & 31, ty = threadIdx.x >> 5;
    #pragma unroll
    for (int j = 0; j < 4; ++j) {
        int k = ty + j * 8;
        tile[k][tx] = (n0 + tx < N) ? W[(size_t)(k0 + k) * N + n0 + tx] : 0.f;
    }
    __syncthreads();
    #pragma unroll
    for (int j = 0; j < 4; ++j) {
        int nrow = ty + j * 8;
        float v = tile[tx][nrow];
        ushort_t h, l;
        split2(v, h, l);
        size_t o = (size_t)(n0 + nrow) * K + k0 + tx;
        Th[o] = h; Tl[o] = l;
    }
}

// ======== 256x256 8-wave pipelined bf16x3 GEMM (counted vmcnt, T2 swizzle) ====
__global__ __launch_bounds__(512, 2) void gemm_mfma3_256(
    const ushort_t* __restrict__ Ah, const ushort_t* __restrict__ Al,
    const ushort_t* __restrict__ Bh, const ushort_t* __restrict__ Bl,
    float* __restrict__ C, int M, int N, int K) {
    __shared__ ushort_t lds[65536];   // 128 KB
    const int tid  = threadIdx.x;
    const int w    = tid >> 6;
    const int lane = tid & 63;
    const int wr = w >> 2;
    const int wc = w & 3;
    const int fr = lane & 15;
    const int kq = (lane >> 4) * 8;
    const int bm = blockIdx.y * 256;
    const int bn = blockIdx.x * 256;
    const int NT = K >> 5;

    const int sg   = tid ^ ((tid >> 3) & 7);
    const int srow = sg >> 2;
    const int skof = (sg & 3) * 8;

    f32x4 acc[8][4];
    #pragma unroll
    for (int i = 0; i < 8; ++i)
        #pragma unroll
        for (int j = 0; j < 4; ++j) acc[i][j] = (f32x4){0.f, 0.f, 0.f, 0.f};

    #define STAGE(t, db)                                                          \
    {                                                                             \
        const int k0_ = (t) * 32;                                                 \
        _Pragma("unroll")                                                         \
        for (int h_ = 0; h_ < 2; ++h_) {                                          \
            const size_t ga_ = (size_t)(bm + h_ * 128 + srow) * K + k0_ + skof;   \
            const size_t gb_ = (size_t)(bn + h_ * 128 + srow) * K + k0_ + skof;   \
            const int dst_ = (db) * 8192 + h_ * 4096 + w * 512;                   \
            __builtin_amdgcn_global_load_lds((gptr_t)(Ah + ga_), (sptr_t)&lds[0     + dst_], 16, 0, 0); \
            __builtin_amdgcn_global_load_lds((gptr_t)(Al + ga_), (sptr_t)&lds[16384 + dst_], 16, 0, 0); \
            __builtin_amdgcn_global_load_lds((gptr_t)(Bh + gb_), (sptr_t)&lds[32768 + dst_], 16, 0, 0); \
            __builtin_amdgcn_global_load_lds((gptr_t)(Bl + gb_), (sptr_t)&lds[49152 + dst_], 16, 0, 0); \
        }                                                                         \
    }

    #define LDF(arrOff, db, row) \
        (*(const short8*)&lds[(arrOff) + (db) * 8192 + \
            ((((row) << 2) | (kq >> 3)) ^ (((row) >> 1) & 7)) * 8])

    STAGE(0, 0);
    STAGE(1, 1);
    asm volatile("s_waitcnt vmcnt(8)" ::: "memory");
    __builtin_amdgcn_s_barrier();

    for (int t = 0; t < NT; ++t) {
        const int db = t & 1;
        short8 bhF[4], blF[4], ahF[4], alF[4];
        #pragma unroll
        for (int j = 0; j < 4; ++j) {
            const int rowb = wc * 64 + j * 16 + fr;
            bhF[j] = LDF(32768, db, rowb);
            blF[j] = LDF(49152, db, rowb);
        }
        #pragma unroll
        for (int i = 0; i < 4; ++i) {
            const int rowa = wr * 128 + i * 16 + fr;
            ahF[i] = LDF(0, db, rowa);
            alF[i] = LDF(16384, db, rowa);
        }
        __builtin_amdgcn_s_setprio(1);
        #pragma unroll
        for (int i = 0; i < 4; ++i)
            #pragma unroll
            for (int j = 0; j < 4; ++j) {
                acc[i][j] = __builtin_amdgcn_mfma_f32_16x16x32_bf16(ahF[i], bhF[j], acc[i][j], 0, 0, 0);
                acc[i][j] = __builtin_amdgcn_mfma_f32_16x16x32_bf16(ahF[i], blF[j], acc[i][j], 0, 0, 0);
                acc[i][j] = __builtin_amdgcn_mfma_f32_16x16x32_bf16(alF[i], bhF[j], acc[i][j], 0, 0, 0);
            }
        __builtin_amdgcn_s_setprio(0);
        short8 ah2[4], al2[4];
        #pragma unroll
        for (int i = 0; i < 4; ++i) {
            const int rowa = wr * 128 + (i + 4) * 16 + fr;
            ah2[i] = LDF(0, db, rowa);
            al2[i] = LDF(16384, db, rowa);
        }
        asm volatile("s_waitcnt lgkmcnt(0)" ::: "memory");
        __builtin_amdgcn_sched_barrier(0);
        __builtin_amdgcn_s_barrier();
        if (t + 2 < NT) STAGE(t + 2, db);
        __builtin_amdgcn_s_setprio(1);
        #pragma unroll
        for (int i = 0; i < 4; ++i)
            #pragma unroll
            for (int j = 0; j < 4; ++j) {
                acc[i + 4][j] = __builtin_amdgcn_mfma_f32_16x16x32_bf16(ah2[i], bhF[j], acc[i + 4][j], 0, 0, 0);
                acc[i + 4][j] = __builtin_amdgcn_mfma_f32_16x16x32_bf16(ah2[i], blF[j], acc[i + 4][j], 0, 0, 0);
                acc[i + 4][j] = __builtin_amdgcn_mfma_f32_16x16x32_bf16(al2[i], bhF[j], acc[i + 4][j], 0, 0, 0);
            }
        __builtin_amdgcn_s_setprio(0);
        if (t + 2 < NT) {
            asm volatile("s_waitcnt vmcnt(8)" ::: "memory");
        } else {
            asm volatile("s_waitcnt vmcnt(0)" ::: "memory");
        }
        __builtin_amdgcn_sched_barrier(0);
        __builtin_amdgcn_s_barrier();
    }
    #undef STAGE
    #undef LDF

    #pragma unroll
    for (int i = 0; i < 8; ++i) {
        const int row = bm + wr * 128 + i * 16 + (lane >> 4) * 4;
        #pragma unroll
        for (int j = 0; j < 4; ++j) {
            const int col = bn + wc * 64 + j * 16 + fr;
            float* cp = C + (size_t)row * N + col;
            #pragma unroll
            for (int r = 0; r < 4; ++r) cp[(size_t)r * N] = acc[i][j][r];
        }
    }
}

// ---------------- bf16x3 MFMA GEMM, tile 128x128, 4 waves (2x2) -------------
// epi==1: C = softplus(acc + bias[col]).
__global__ __launch_bounds__(256) void gemm_mfma3(
    const ushort_t* __restrict__ Ah, const ushort_t* __restrict__ Al,
    const ushort_t* __restrict__ Bh, const ushort_t* __restrict__ Bl,
    float* __restrict__ C, int M, int N, int K,
    const float* __restrict__ bias, int epi) {
    __shared__ ushort_t sAh[4096], sAl[4096], sBh[4096], sBl[4096];
    const int tid  = threadIdx.x;
    const int wid  = tid >> 6;
    const int lane = tid & 63;
    const int bm = blockIdx.y * 128;
    const int bn = blockIdx.x * 128;
    const int wr = wid >> 1, wc = wid & 1;

    f32x4 acc[4][4];
    #pragma unroll
    for (int i = 0; i < 4; ++i)
        #pragma unroll
        for (int j = 0; j < 4; ++j) acc[i][j] = (f32x4){0.f, 0.f, 0.f, 0.f};

    for (int k0 = 0; k0 < K; k0 += 32) {
        #pragma unroll
        for (int issue = 0; issue < 2; ++issue) {
            const int off = wid * 2048 + issue * 1024 + lane * 16;
            const int row = off >> 6;
            const int ce  = (off & 63) >> 1;
            const size_t ga = (size_t)(bm + row) * K + k0 + ce;
            const size_t gb = (size_t)(bn + row) * K + k0 + ce;
            const int lo = (wid * 2048 + issue * 1024) >> 1;
            __builtin_amdgcn_global_load_lds((gptr_t)(Ah + ga), (sptr_t)&sAh[lo], 16, 0, 0);
            __builtin_amdgcn_global_load_lds((gptr_t)(Al + ga), (sptr_t)&sAl[lo], 16, 0, 0);
            __builtin_amdgcn_global_load_lds((gptr_t)(Bh + gb), (sptr_t)&sBh[lo], 16, 0, 0);
            __builtin_amdgcn_global_load_lds((gptr_t)(Bl + gb), (sptr_t)&sBl[lo], 16, 0, 0);
        }
        __syncthreads();

        const int fr = lane & 15;
        const int kb = (lane >> 4) * 8;
        short8 ah[4], al[4], bh[4], bl[4];
        #pragma unroll
        for (int i = 0; i < 4; ++i) {
            const int ra = (wr * 64 + i * 16 + fr) * 32 + kb;
            ah[i] = *(const short8*)&sAh[ra];
            al[i] = *(const short8*)&sAl[ra];
            const int rb = (wc * 64 + i * 16 + fr) * 32 + kb;
            bh[i] = *(const short8*)&sBh[rb];
            bl[i] = *(const short8*)&sBl[rb];
        }
        #pragma unroll
        for (int i = 0; i < 4; ++i)
            #pragma unroll
            for (int j = 0; j < 4; ++j) {
                acc[i][j] = __builtin_amdgcn_mfma_f32_16x16x32_bf16(ah[i], bh[j], acc[i][j], 0, 0, 0);
                acc[i][j] = __builtin_amdgcn_mfma_f32_16x16x32_bf16(ah[i], bl[j], acc[i][j], 0, 0, 0);
                acc[i][j] = __builtin_amdgcn_mfma_f32_16x16x32_bf16(al[i], bh[j], acc[i][j], 0, 0, 0);
            }
        __syncthreads();
    }

    #pragma unroll
    for (int i = 0; i < 4; ++i) {
        int row = bm + wr * 64 + i * 16 + (lane >> 4) * 4;
        #pragma unroll
        for (int j = 0; j < 4; ++j) {
            int col = bn + wc * 64 + j * 16 + (lane & 15);
            float* cp = C + (size_t)row * N + col;
            #pragma unroll
            for (int r = 0; r < 4; ++r) {
                float v = acc[i][j][r];
                if (epi == 1) {
                    v += bias[col];
                    v = (v > 20.f) ? v : log1pf(__expf(v));
                }
                cp[(size_t)r * N] = v;
            }
        }
    }
}

// ---- 128x64-tile variant (4 waves as 2Mx2N, per-wave 64x32) for out-proj ----
__global__ __launch_bounds__(256) void gemm_mfma3_n64(
    const ushort_t* __restrict__ Ah, const ushort_t* __restrict__ Al,
    const ushort_t* __restrict__ Bh, const ushort_t* __restrict__ Bl,
    float* __restrict__ C, int M, int N, int K) {
    __shared__ ushort_t sAh[4096], sAl[4096], sBh[2048], sBl[2048];
    const int tid  = threadIdx.x;
    const int wid  = tid >> 6;
    const int lane = tid & 63;
    const int bm = blockIdx.y * 128;
    const int bn = blockIdx.x * 64;
    const int wr = wid >> 1, wc = wid & 1;

    f32x4 acc[4][2];
    #pragma unroll
    for (int i = 0; i < 4; ++i)
        #pragma unroll
        for (int j = 0; j < 2; ++j) acc[i][j] = (f32x4){0.f, 0.f, 0.f, 0.f};

    for (int k0 = 0; k0 < K; k0 += 32) {
        #pragma unroll
        for (int issue = 0; issue < 2; ++issue) {
            const int off = issue * 4096 + tid * 16;
            const int row = off >> 6;
            const int ce  = (off & 63) >> 1;
            const size_t ga = (size_t)(bm + row) * K + k0 + ce;
            const int lo = (issue * 4096 + wid * 1024) >> 1;
            __builtin_amdgcn_global_load_lds((gptr_t)(Ah + ga), (sptr_t)&sAh[lo], 16, 0, 0);
            __builtin_amdgcn_global_load_lds((gptr_t)(Al + ga), (sptr_t)&sAl[lo], 16, 0, 0);
        }
        {
            const int off = tid * 16;
            const int row = off >> 6;
            const int ce  = (off & 63) >> 1;
            const size_t gb = (size_t)(bn + row) * K + k0 + ce;
            const int lo = (wid * 1024) >> 1;
            __builtin_amdgcn_global_load_lds((gptr_t)(Bh + gb), (sptr_t)&sBh[lo], 16, 0, 0);
            __builtin_amdgcn_global_load_lds((gptr_t)(Bl + gb), (sptr_t)&sBl[lo], 16, 0, 0);
        }
        __syncthreads();

        const int fr = lane & 15;
        const int kb = (lane >> 4) * 8;
        short8 ah[4], al[4], bh[2], bl[2];
        #pragma unroll
        for (int i = 0; i < 4; ++i) {
            const int ra = (wr * 64 + i * 16 + fr) * 32 + kb;
            ah[i] = *(const short8*)&sAh[ra];
            al[i] = *(const short8*)&sAl[ra];
        }
        #pragma unroll
        for (int j = 0; j < 2; ++j) {
            const int rb = (wc * 32 + j * 16 + fr) * 32 + kb;
            bh[j] = *(const short8*)&sBh[rb];
            bl[j] = *(const short8*)&sBl[rb];
        }
        #pragma unroll
        for (int i = 0; i < 4; ++i)
            #pragma unroll
            for (int j = 0; j < 2; ++j) {
                acc[i][j] = __builtin_amdgcn_mfma_f32_16x16x32_bf16(ah[i], bh[j], acc[i][j], 0, 0, 0);
                acc[i][j] = __builtin_amdgcn_mfma_f32_16x16x32_bf16(ah[i], bl[j], acc[i][j], 0, 0, 0);
                acc[i][j] = __builtin_amdgcn_mfma_f32_16x16x32_bf16(al[i], bh[j], acc[i][j], 0, 0, 0);
            }
        __syncthreads();
    }

    #pragma unroll
    for (int i = 0; i < 4; ++i) {
        int row = bm + wr * 64 + i * 16 + (lane >> 4) * 4;
        #pragma unroll
        for (int j = 0; j < 2; ++j) {
            int col = bn + wc * 32 + j * 16 + (lane & 15);
            float* cp = C + (size_t)row * N + col;
            #pragma unroll
            for (int r = 0; r < 4; ++r) cp[(size_t)r * N] = acc[i][j][r];
        }
    }
}

// Split-K=16 for xdbl = xs @ W_x (M=4096, Npad=128 but only 96 stored).
__global__ __launch_bounds__(256) void gemm_mfma3_sk(
    const ushort_t* __restrict__ Ah, const ushort_t* __restrict__ Al,
    const ushort_t* __restrict__ Bh, const ushort_t* __restrict__ Bl,
    float* __restrict__ partial, int K) {
    __shared__ ushort_t sAh[4096], sAl[4096], sBh[4096], sBl[4096];
    const int tid  = threadIdx.x;
    const int wid  = tid >> 6;
    const int lane = tid & 63;
    const int kslice = blockIdx.x;
    const int bm = blockIdx.y * 128;
    const int wr = wid >> 1, wc = wid & 1;
    const int kbeg = kslice * 128;

    f32x4 acc[4][4];
    #pragma unroll
    for (int i = 0; i < 4; ++i)
        #pragma unroll
        for (int j = 0; j < 4; ++j) acc[i][j] = (f32x4){0.f, 0.f, 0.f, 0.f};

    for (int k0 = kbeg; k0 < kbeg + 128; k0 += 32) {
        #pragma unroll
        for (int issue = 0; issue < 2; ++issue) {
            const int off = wid * 2048 + issue * 1024 + lane * 16;
            const int row = off >> 6;
            const int ce  = (off & 63) >> 1;
            const size_t ga = (size_t)(bm + row) * K + k0 + ce;
            const size_t gb = (size_t)row * K + k0 + ce;
            const int lo = (wid * 2048 + issue * 1024) >> 1;
            __builtin_amdgcn_global_load_lds((gptr_t)(Ah + ga), (sptr_t)&sAh[lo], 16, 0, 0);
            __builtin_amdgcn_global_load_lds((gptr_t)(Al + ga), (sptr_t)&sAl[lo], 16, 0, 0);
            __builtin_amdgcn_global_load_lds((gptr_t)(Bh + gb), (sptr_t)&sBh[lo], 16, 0, 0);
            __builtin_amdgcn_global_load_lds((gptr_t)(Bl + gb), (sptr_t)&sBl[lo], 16, 0, 0);
        }
        __syncthreads();

        const int fr = lane & 15;
        const int kb = (lane >> 4) * 8;
        short8 ah[4], al[4], bh[4], bl[4];
        #pragma unroll
        for (int i = 0; i < 4; ++i) {
            const int ra = (wr * 64 + i * 16 + fr) * 32 + kb;
            ah[i] = *(const short8*)&sAh[ra];
            al[i] = *(const short8*)&sAl[ra];
            const int rb = (wc * 64 + i * 16 + fr) * 32 + kb;
            bh[i] = *(const short8*)&sBh[rb];
            bl[i] = *(const short8*)&sBl[rb];
        }
        #pragma unroll
        for (int i = 0; i < 4; ++i)
            #pragma unroll
            for (int j = 0; j < 4; ++j) {
                acc[i][j] = __builtin_amdgcn_mfma_f32_16x16x32_bf16(ah[i], bh[j], acc[i][j], 0, 0, 0);
                acc[i][j] = __builtin_amdgcn_mfma_f32_16x16x32_bf16(ah[i], bl[j], acc[i][j], 0, 0, 0);
                acc[i][j] = __builtin_amdgcn_mfma_f32_16x16x32_bf16(al[i], bh[j], acc[i][j], 0, 0, 0);
            }
        __syncthreads();
    }

    float* Cp = partial + (size_t)kslice * 4096 * 96;
    #pragma unroll
    for (int i = 0; i < 4; ++i) {
        int row = bm + wr * 64 + i * 16 + (lane >> 4) * 4;
        #pragma unroll
        for (int j = 0; j < 4; ++j) {
            int col = wc * 64 + j * 16 + (lane & 15);
            if (col < 96) {
                float* cp = Cp + (size_t)row * 96 + col;
                #pragma unroll
                for (int r = 0; r < 4; ++r) cp[(size_t)r * 96] = acc[i][j][r];
            }
        }
    }
}

// xdbl[row][c] = sum of 16 slices (partial packed N=96); xdbl stored with
// row stride 128 (cols 96..127 unwritten). Also emit bf16 split of cols 0..63.
__global__ void reduce16split(const float4* __restrict__ p, float4* __restrict__ xdbl4,
                              ushort_t* __restrict__ dh, ushort_t* __restrict__ dl) {
    int i = blockIdx.x * 256 + threadIdx.x;   // 4096*24 = 98,304 float4s per slice
    float4 s = p[i];
    #pragma unroll
    for (int k = 1; k < 16; ++k) {
        float4 v = p[i + k * 98304];
        s.x += v.x; s.y += v.y; s.z += v.z; s.w += v.w;
    }
    int row = i / 24;
    int c4  = i - row * 24;
    xdbl4[row * 32 + c4] = s;
    if (c4 < 16) {                  // cols 0..63 -> delta-GEMM A operand
        ushort4 hh, ll;
        split2(s.x, hh.x, ll.x); split2(s.y, hh.y, ll.y);
        split2(s.z, hh.z, ll.z); split2(s.w, hh.w, ll.w);
        ((ushort4*)dh)[row * 16 + c4] = hh;
        ((ushort4*)dl)[row * 16 + c4] = ll;
    }
}

// ---------------- conv + silu -> xs as bf16 hi/lo ----------------
__global__ void conv_silu_k(const float* __restrict__ xr, const float* __restrict__ Wc,
                            const float* __restrict__ bc,
                            ushort_t* __restrict__ xsh, ushort_t* __restrict__ xsl,
                            int total) {
    for (int idx = blockIdx.x * blockDim.x + threadIdx.x; idx < total;
         idx += gridDim.x * blockDim.x) {
        int d = idx & 2047;
        int l = (idx >> 11) & 2047;
        int b = idx >> 22;
        float acc = bc[d];
        const float* wp = Wc + d * 4;
        #pragma unroll
        for (int k = 0; k < 4; ++k) {
            int ll = l - 3 + k;
            if (ll >= 0)
                acc = fmaf(xr[((size_t)(b * 2048 + ll) << 12) + d], wp[k], acc);
        }
        float v = acc / (1.f + __expf(-acc));
        ushort_t h, lo;
        split2(v, h, lo);
        xsh[idx] = h;
        xsl[idx] = lo;
    }
}

// ---------------- chunked selective scan, n in registers ----------------
__global__ __launch_bounds__(256) void scan_p1(
    const float* __restrict__ delta,
    const ushort_t* __restrict__ xsh, const ushort_t* __restrict__ xsl,
    const float* __restrict__ xdbl, const float* __restrict__ A_log,
    float* __restrict__ S, float* __restrict__ sumdt) {
    const int u = blockIdx.x * 256 + threadIdx.x;
    const int chunk = u >> 12;
    const int c = u & 4095;
    const int b = c >> 11, d = c & 2047;

    float a[16];
    #pragma unroll
    for (int i = 0; i < 4; ++i) {
        float4 v = ((const float4*)(A_log + d * 16))[i];
        a[4 * i + 0] = -__expf(v.x); a[4 * i + 1] = -__expf(v.y);
        a[4 * i + 2] = -__expf(v.z); a[4 * i + 3] = -__expf(v.w);
    }
    float h[16];
    #pragma unroll
    for (int n = 0; n < 16; ++n) h[n] = 0.f;
    float sdt = 0.f;

    const size_t row0 = (size_t)b * 2048 + (size_t)chunk * CL;
    const float4* xd4 = (const float4*)xdbl;
    #pragma unroll 2
    for (int t = 0; t < CL; ++t) {
        const size_t row = row0 + t;
        float dt = delta[row * 2048 + d];
        float xv = bf2f(xsh[row * 2048 + d]) + bf2f(xsl[row * 2048 + d]);
        float4 Bv[4];
        #pragma unroll
        for (int i = 0; i < 4; ++i) Bv[i] = xd4[row * 32 + 16 + i];
        const float* Bf = (const float*)Bv;
        sdt += dt;
        float du = dt * xv;
        #pragma unroll
        for (int n = 0; n < 16; ++n) {
            float dA = __expf(dt * a[n]);
            h[n] = fmaf(dA, h[n], du * Bf[n]);
        }
    }
    float4* S4 = (float4*)(S + ((size_t)chunk * 4096 + c) * 16);
    #pragma unroll
    for (int i = 0; i < 4; ++i)
        S4[i] = make_float4(h[4 * i + 0], h[4 * i + 1], h[4 * i + 2], h[4 * i + 3]);
    sumdt[chunk * 4096 + c] = sdt;
}

__global__ __launch_bounds__(256) void scan_p2(
    float* __restrict__ S, const float* __restrict__ sumdt,
    const float* __restrict__ A_log) {
    const int idx = blockIdx.x * blockDim.x + threadIdx.x;
    const int n = idx & 15;
    const int c = (idx >> 4) & 4095;
    const int d = c & 2047;
    const float a = -__expf(A_log[d * 16 + n]);
    float h = 0.f;
    for (int k = 0; k < NC; ++k) {
        const size_t o = ((size_t)k * 4096 + c) * 16 + n;
        float carry = S[o];
        S[o] = h;
        float P = __expf(a * sumdt[k * 4096 + c]);
        h = fmaf(P, h, carry);
    }
}

__global__ __launch_bounds__(256) void scan_p3(
    const float* __restrict__ delta,
    const ushort_t* __restrict__ xsh, const ushort_t* __restrict__ xsl,
    const float* __restrict__ xdbl, const float* __restrict__ xr,
    const float* __restrict__ A_log, const float* __restrict__ Dp,
    const float* __restrict__ H0,
    ushort_t* __restrict__ yh, ushort_t* __restrict__ yl) {
    const int u = blockIdx.x * 256 + threadIdx.x;
    const int chunk = u >> 12;
    const int c = u & 4095;
    const int b = c >> 11, d = c & 2047;

    float a[16];
    #pragma unroll
    for (int i = 0; i < 4; ++i) {
        float4 v = ((const float4*)(A_log + d * 16))[i];
        a[4 * i + 0] = -__expf(v.x); a[4 * i + 1] = -__expf(v.y);
        a[4 * i + 2] = -__expf(v.z); a[4 * i + 3] = -__expf(v.w);
    }
    float h[16];
    const float4* H4 = (const float4*)(H0 + ((size_t)chunk * 4096 + c) * 16);
    #pragma unroll
    for (int i = 0; i < 4; ++i) {
        float4 v = H4[i];
        h[4 * i + 0] = v.x; h[4 * i + 1] = v.y; h[4 * i + 2] = v.z; h[4 * i + 3] = v.w;
    }
    const float Dd = Dp[d];

    const size_t row0 = (size_t)b * 2048 + (size_t)chunk * CL;
    const float4* xd4 = (const float4*)xdbl;
    #pragma unroll 2
    for (int t = 0; t < CL; ++t) {
        const size_t row = row0 + t;
        float dt = delta[row * 2048 + d];
        float xv = bf2f(xsh[row * 2048 + d]) + bf2f(xsl[row * 2048 + d]);
        float4 BC[8];
        #pragma unroll
        for (int i = 0; i < 8; ++i) BC[i] = xd4[row * 32 + 16 + i];
        const float* Bf = (const float*)BC;
        const float* Cf = Bf + 16;
        float du = dt * xv;
        float acc = 0.f;
        #pragma unroll
        for (int n = 0; n < 16; ++n) {
            float dA = __expf(dt * a[n]);
            h[n] = fmaf(dA, h[n], du * Bf[n]);
            acc = fmaf(h[n], Cf[n], acc);
        }
        float rv = xr[(row << 12) + 2048 + d];
        float yv = fmaf(Dd, xv, acc) * (rv / (1.f + __expf(-rv)));
        ushort_t hb, lb;
        split2(yv, hb, lb);
        yh[row * 2048 + d] = hb;
        yl[row * 2048 + d] = lb;
    }
}

// ---------------- launch ----------------
extern "C" void kernel_launch(void* const* d_in, const int* in_sizes, int n_in,
                              void* d_out, int out_size, void* d_ws, size_t ws_size,
                              hipStream_t stream) {
    const float* x      = (const float*)d_in[0];
    const float* W_in   = (const float*)d_in[1];
    const float* W_conv = (const float*)d_in[2];
    const float* b_conv = (const float*)d_in[3];
    const float* W_x    = (const float*)d_in[4];
    const float* W_dt   = (const float*)d_in[5];
    const float* b_dt   = (const float*)d_in[6];
    const float* A_log  = (const float*)d_in[7];
    const float* Dp     = (const float*)d_in[8];
    const float* W_out  = (const float*)d_in[9];
    float* out = (float*)d_out;

    float* ws    = (float*)d_ws;
    float* xr    = ws;                      // 16,777,216 f
    float* xdbl  = xr + 16777216;           //    524,288 f (4096 x 128)
    float* delta = xdbl + 524288;           //  8,388,608 f
    float* S     = delta + 8388608;         //  4,194,304 f
    float* sumdt = S + 4194304;             //    262,144 f
    ushort_t* base = (ushort_t*)(sumdt + 262144);
    ushort_t* xh = base, *xl = base + 4194304;
    ushort_t* winh = base + 8388608, *winl = base + 12582912;
    float*    partial = (float*)base;                 // sk partials (25.2 MB)
    ushort_t* yh = base, *yl = base + 8388608;        // written in p3
    ushort_t* wouth = base + 16777216, *woutl = base + 18874368;
    ushort_t* wxh   = base + 20971520, *wxl   = base + 21233664;
    ushort_t* wdth  = base + 21495808, *wdtl  = base + 21626880;
    ushort_t* dAh   = base + 21757952, *dAl   = base + 22020096;
    ushort_t* xsh   = base + 22282240, *xsl   = base + 30670848;

    dim3 blk(256);

    convert_all<<<dim3(10624), blk, 0, stream>>>(x, xh, xl, W_in, winh, winl,
                                                 W_out, wouth, woutl,
                                                 W_x, wxh, wxl, W_dt, wdth, wdtl);

    // 1) xr = x @ W_in   (4096 x 4096 x 1024), pipelined 256x256
    gemm_mfma3_256<<<dim3(16, 16), dim3(512), 0, stream>>>(
        xh, xl, winh, winl, xr, 4096, 4096, 1024);
    // 2) xs = silu(dwconv(xr[:, :2048]) + b_conv) -> bf16 hi/lo
    conv_silu_k<<<dim3(4096), blk, 0, stream>>>(xr, W_conv, b_conv, xsh, xsl, 8388608);
    // 3) xdbl = xs @ W_x  (split-K=16 MFMA + reduce)
    gemm_mfma3_sk<<<dim3(16, 32), blk, 0, stream>>>(xsh, xsl, wxh, wxl, partial, 2048);
    reduce16split<<<dim3(384), blk, 0, stream>>>((const float4*)partial, (float4*)xdbl,
                                                 dAh, dAl);
    // 4) delta = softplus(xdbl[:, :64] @ W_dt + b_dt)  (4096 x 2048 x 64), MFMA
    gemm_mfma3<<<dim3(16, 32), blk, 0, stream>>>(dAh, dAl, wdth, wdtl, delta,
                                                 4096, 2048, 64, b_dt, 1);
    // 5) chunked scan (NC=64, CL=32)
    scan_p1<<<dim3(1024), blk, 0, stream>>>(delta, xsh, xsl, xdbl, A_log, S, sumdt);
    scan_p2<<<dim3(256), blk, 0, stream>>>(S, sumdt, A_log);
    scan_p3<<<dim3(1024), blk, 0, stream>>>(delta, xsh, xsl, xdbl, xr, A_log, Dp, S, yh, yl);
    // 6) out = y @ W_out  (4096 x 1024 x 2048), 128x64-tile (512 blocks)
    gemm_mfma3_n64<<<dim3(16, 32), blk, 0, stream>>>(yh, yl, wouth, woutl, out,
                                                     4096, 1024, 2048);
}